// Round 4
// baseline (760.083 us; speedup 1.0000x reference)
//
#include <hip/hip_runtime.h>
#include <math.h>

// ---------------------------------------------------------------------------
// GATv2 x2 (heads=1) with mean-filled self-loops, fp32 end-to-end.
// Strategy: build CSR-by-dst once (self-loop appended per node), then per
// layer: dense transforms xl=x@Wl, xr=x@Wr, and a per-node wave-parallel
// online-softmax aggregation pass (no atomics in the hot path).
// ---------------------------------------------------------------------------

#define NEG_SLOPE 0.2f

// --- Phase A: in-degree + edge_attr sum per dst ----------------------------
__global__ void degree_kernel(const int* __restrict__ dst, const float* __restrict__ eattr,
                              int* __restrict__ deg, float* __restrict__ asum, int E) {
    int e = blockIdx.x * blockDim.x + threadIdx.x;
    if (e < E) {
        int d = dst[e];
        atomicAdd(&deg[d], 1);
        atomicAdd(&asum[d], eattr[e]);
    }
}

// --- Phase B: row_ptr[i] = prefix sum of (deg[i] + 1) (self-loop slot) -----
__global__ void scan_rowptr_kernel(const int* __restrict__ deg, int* __restrict__ row_ptr, int n) {
    __shared__ int buf[1024];
    __shared__ int carry_s;
    const int t = threadIdx.x;
    if (t == 0) { carry_s = 0; row_ptr[0] = 0; }
    __syncthreads();
    for (int base = 0; base < n; base += 1024) {
        int v = (base + t < n) ? (deg[base + t] + 1) : 0;
        buf[t] = v;
        __syncthreads();
        for (int off = 1; off < 1024; off <<= 1) {
            int add = (t >= off) ? buf[t - off] : 0;
            __syncthreads();
            buf[t] += add;
            __syncthreads();
        }
        int incl = buf[t];
        int carry = carry_s;
        if (base + t < n) row_ptr[base + t + 1] = carry + incl;
        __syncthreads();
        if (t == 1023) carry_s = carry + incl;  // buf[1023] == chunk total
        __syncthreads();
    }
}

// --- Phase C: scatter edges into CSR; append self-loop with mean attr ------
__global__ void csr_fill_kernel(const int* __restrict__ src, const int* __restrict__ dst,
                                const float* __restrict__ eattr,
                                const int* __restrict__ deg, const float* __restrict__ asum,
                                const int* __restrict__ row_ptr, int* __restrict__ fill,
                                int* __restrict__ csr_src, float* __restrict__ csr_attr,
                                int E, int n) {
    int i = blockIdx.x * blockDim.x + threadIdx.x;
    if (i < E) {
        int d = dst[i];
        int pos = row_ptr[d] + atomicAdd(&fill[d], 1);
        csr_src[pos] = src[i];
        csr_attr[pos] = eattr[i];
    } else if (i < E + n) {
        int v = i - E;
        int pos = row_ptr[v] + atomicAdd(&fill[v], 1);
        int c = deg[v];
        csr_src[pos] = v;
        csr_attr[pos] = asum[v] / (float)(c > 0 ? c : 1);   // mean, 0 if isolated
    }
}

// --- Dense transforms: XL = X@Wl, XR = X@Wr (one block per node) -----------
// blockDim = 2*COUT; threads [0,COUT) -> Wl column, [COUT,2*COUT) -> Wr column.
template <int CIN, int COUT>
__global__ void xform_kernel(const float* __restrict__ X, const float* __restrict__ Wl,
                             const float* __restrict__ Wr, float* __restrict__ XL,
                             float* __restrict__ XR, int n) {
    int node = blockIdx.x;
    if (node >= n) return;
    int t = threadIdx.x;
    const float* __restrict__ W = (t < COUT) ? Wl : Wr;
    float* __restrict__ Y = (t < COUT) ? XL : XR;
    int c = t & (COUT - 1);
    const float* __restrict__ xrow = X + (size_t)node * CIN;
    float acc = 0.f;
#pragma unroll 8
    for (int k = 0; k < CIN; ++k)
        acc = fmaf(xrow[k], W[k * COUT + c], acc);
    Y[(size_t)node * COUT + c] = acc;
}

// --- Aggregation, C=128: one wave per node, lane owns channels {2l, 2l+1} --
// NOTE: XR may alias OUT (h overwrites xr1). Each wave reads only its own
// node's XR row (into registers, up front) and writes only its own OUT row,
// so the aliasing is hazard-free; restrict deliberately omitted on XR/OUT.
__global__ __launch_bounds__(256) void agg_c128_kernel(
    const float* __restrict__ XL, const float* XR,
    const int* __restrict__ row_ptr, const int* __restrict__ csr_src,
    const float* __restrict__ csr_attr, const float* __restrict__ We,
    const float* __restrict__ att, const float* __restrict__ bias,
    float* OUT, int n) {
    int wave = threadIdx.x >> 6;
    int lane = threadIdx.x & 63;
    int node = blockIdx.x * 4 + wave;
    if (node >= n) return;

    const float2 xr  = *(const float2*)(XR  + (size_t)node * 128 + lane * 2);
    const float2 wev = *(const float2*)(We  + lane * 2);
    const float2 atv = *(const float2*)(att + lane * 2);
    const float2 bv  = *(const float2*)(bias + lane * 2);

    int p = row_ptr[node], pe = row_ptr[node + 1];
    float m = -INFINITY, s = 0.f, a0 = 0.f, a1 = 0.f;
    for (; p < pe; ++p) {
        int   sj = csr_src[p];
        float ae = csr_attr[p];
        float2 xl = *(const float2*)(XL + (size_t)sj * 128 + lane * 2);
        float z0 = xl.x + xr.x + ae * wev.x;
        float z1 = xl.y + xr.y + ae * wev.y;
        z0 = (z0 > 0.f) ? z0 : NEG_SLOPE * z0;
        z1 = (z1 > 0.f) ? z1 : NEG_SLOPE * z1;
        float part = fmaf(atv.x, z0, atv.y * z1);
#pragma unroll
        for (int off = 32; off > 0; off >>= 1) part += __shfl_xor(part, off, 64);
        // online softmax update (identical math to max-subtracted softmax)
        float nm = fmaxf(m, part);
        float sc = expf(m - nm);      // first iter: expf(-inf)=0
        float w  = expf(part - nm);
        s  = s  * sc + w;
        a0 = a0 * sc + w * xl.x;
        a1 = a1 * sc + w * xl.y;
        m = nm;
    }
    float inv = 1.f / (s + 1e-16f);
    float o0 = a0 * inv + bv.x;
    float o1 = a1 * inv + bv.y;
    o0 = (o0 > 0.f) ? o0 : (expf(o0) - 1.f);   // elu
    o1 = (o1 > 0.f) ? o1 : (expf(o1) - 1.f);
    *(float2*)(OUT + (size_t)node * 128 + lane * 2) = make_float2(o0, o1);
}

// --- Aggregation, C=64: one wave per node, lane owns channel l -------------
__global__ __launch_bounds__(256) void agg_c64_kernel(
    const float* __restrict__ XL, const float* __restrict__ XR,
    const int* __restrict__ row_ptr, const int* __restrict__ csr_src,
    const float* __restrict__ csr_attr, const float* __restrict__ We,
    const float* __restrict__ att, const float* __restrict__ bias,
    float* __restrict__ OUT, int n) {
    int wave = threadIdx.x >> 6;
    int lane = threadIdx.x & 63;
    int node = blockIdx.x * 4 + wave;
    if (node >= n) return;

    float xr  = XR[(size_t)node * 64 + lane];
    float wev = We[lane];
    float atv = att[lane];
    float bv  = bias[lane];

    int p = row_ptr[node], pe = row_ptr[node + 1];
    float m = -INFINITY, s = 0.f, a0 = 0.f;
    for (; p < pe; ++p) {
        int   sj = csr_src[p];
        float ae = csr_attr[p];
        float xl = XL[(size_t)sj * 64 + lane];
        float z = xl + xr + ae * wev;
        z = (z > 0.f) ? z : NEG_SLOPE * z;
        float part = atv * z;
#pragma unroll
        for (int off = 32; off > 0; off >>= 1) part += __shfl_xor(part, off, 64);
        float nm = fmaxf(m, part);
        float sc = expf(m - nm);
        float w  = expf(part - nm);
        s  = s  * sc + w;
        a0 = a0 * sc + w * xl;
        m = nm;
    }
    float o = a0 / (s + 1e-16f) + bv;
    o = (o > 0.f) ? o : (expf(o) - 1.f);       // elu
    OUT[(size_t)node * 64 + lane] = o;
}

// ---------------------------------------------------------------------------
extern "C" void kernel_launch(void* const* d_in, const int* in_sizes, int n_in,
                              void* d_out, int out_size, void* d_ws, size_t ws_size,
                              hipStream_t stream) {
    const float* x    = (const float*)d_in[0];
    const int*   eidx = (const int*)  d_in[1];
    const float* ea   = (const float*)d_in[2];
    const float* Wl1  = (const float*)d_in[3];
    const float* Wr1  = (const float*)d_in[4];
    const float* We1  = (const float*)d_in[5];
    const float* att1 = (const float*)d_in[6];
    const float* b1   = (const float*)d_in[7];
    const float* Wl2  = (const float*)d_in[8];
    const float* Wr2  = (const float*)d_in[9];
    const float* We2  = (const float*)d_in[10];
    const float* att2 = (const float*)d_in[11];
    const float* b2   = (const float*)d_in[12];

    const int FIN = 128, H = 128, OUTC = 64;
    const int E  = in_sizes[2];          // edge_attr element count = #edges
    const int N  = in_sizes[0] / FIN;
    const int EP = E + N;                // with self-loops
    const int* src = eidx;               // edge_index[0]
    const int* dst = eidx + E;           // edge_index[1]

    // ---- workspace layout (256B aligned), peak ≈ 59 MB ----
    char* ws = (char*)d_ws;
    size_t off = 0;
    auto alloc = [&](size_t bytes) {
        size_t o = off;
        off += (bytes + 255) & ~(size_t)255;
        return o;
    };
    size_t deg_off  = alloc((size_t)N * 4);
    size_t asum_off = alloc((size_t)N * 4);
    size_t fill_off = alloc((size_t)N * 4);
    size_t zero_bytes = off;                       // deg|asum|fill zeroed together
    size_t rp_off    = alloc((size_t)(N + 1) * 4);
    size_t csrc_off  = alloc((size_t)EP * 4);
    size_t cattr_off = alloc((size_t)EP * 4);
    size_t xl1_off   = alloc((size_t)N * H * 4);   // reused as xl2|xr2 for layer 2
    size_t xr1_off   = alloc((size_t)N * H * 4);   // reused as h (safe aliasing)

    int*   deg   = (int*)  (ws + deg_off);
    float* asum  = (float*)(ws + asum_off);
    int*   fill  = (int*)  (ws + fill_off);
    int*   rp    = (int*)  (ws + rp_off);
    int*   csrc  = (int*)  (ws + csrc_off);
    float* cattr = (float*)(ws + cattr_off);
    float* xl1   = (float*)(ws + xl1_off);
    float* xr1   = (float*)(ws + xr1_off);
    float* h     = xr1;                                        // aliases xr1
    float* xl2   = (float*)(ws + xl1_off);                     // reuse xl1 region
    float* xr2   = (float*)(ws + xl1_off + (size_t)N * OUTC * 4);

    (void)ws_size; (void)n_in; (void)out_size;

    hipMemsetAsync(ws, 0, zero_bytes, stream);

    const int TB = 256;
    degree_kernel<<<(E + TB - 1) / TB, TB, 0, stream>>>(dst, ea, deg, asum, E);
    scan_rowptr_kernel<<<1, 1024, 0, stream>>>(deg, rp, N);
    csr_fill_kernel<<<(EP + TB - 1) / TB, TB, 0, stream>>>(src, dst, ea, deg, asum,
                                                           rp, fill, csrc, cattr, E, N);
    // layer 1
    xform_kernel<128, 128><<<N, 256, 0, stream>>>(x, Wl1, Wr1, xl1, xr1, N);
    agg_c128_kernel<<<(N + 3) / 4, 256, 0, stream>>>(xl1, xr1, rp, csrc, cattr,
                                                     We1, att1, b1, h, N);
    // layer 2
    xform_kernel<128, 64><<<N, 128, 0, stream>>>(h, Wl2, Wr2, xl2, xr2, N);
    agg_c64_kernel<<<(N + 3) / 4, 256, 0, stream>>>(xl2, xr2, rp, csrc, cattr,
                                                    We2, att2, b2, (float*)d_out, N);
}

// Round 5
// 574.795 us; speedup vs baseline: 1.3224x; 1.3224x over previous
//
#include <hip/hip_runtime.h>
#include <math.h>

// ---------------------------------------------------------------------------
// GATv2 x2 (heads=1) with mean-filled self-loops, fp32 end-to-end.
// CSR-by-dst built once (self-loop appended per node); per layer: LDS-tiled
// dense transforms xl=x@Wl, xr=x@Wr, then per-node wave-parallel
// online-softmax aggregation (no atomics in the hot path).
// ---------------------------------------------------------------------------

#define NEG_SLOPE 0.2f

// --- Phase A: in-degree + edge_attr sum per dst ----------------------------
__global__ void degree_kernel(const int* __restrict__ dst, const float* __restrict__ eattr,
                              int* __restrict__ deg, float* __restrict__ asum, int E) {
    int e = blockIdx.x * blockDim.x + threadIdx.x;
    if (e < E) {
        int d = dst[e];
        atomicAdd(&deg[d], 1);
        atomicAdd(&asum[d], eattr[e]);
    }
}

// --- Phase B: row_ptr[i] = prefix sum of (deg[i] + 1) (self-loop slot) -----
__global__ void scan_rowptr_kernel(const int* __restrict__ deg, int* __restrict__ row_ptr, int n) {
    __shared__ int buf[1024];
    __shared__ int carry_s;
    const int t = threadIdx.x;
    if (t == 0) { carry_s = 0; row_ptr[0] = 0; }
    __syncthreads();
    for (int base = 0; base < n; base += 1024) {
        int v = (base + t < n) ? (deg[base + t] + 1) : 0;
        buf[t] = v;
        __syncthreads();
        for (int off = 1; off < 1024; off <<= 1) {
            int add = (t >= off) ? buf[t - off] : 0;
            __syncthreads();
            buf[t] += add;
            __syncthreads();
        }
        int incl = buf[t];
        int carry = carry_s;
        if (base + t < n) row_ptr[base + t + 1] = carry + incl;
        __syncthreads();
        if (t == 1023) carry_s = carry + incl;  // buf[1023] == chunk total
        __syncthreads();
    }
}

// --- Phase C: scatter edges into CSR; append self-loop with mean attr ------
__global__ void csr_fill_kernel(const int* __restrict__ src, const int* __restrict__ dst,
                                const float* __restrict__ eattr,
                                const int* __restrict__ deg, const float* __restrict__ asum,
                                const int* __restrict__ row_ptr, int* __restrict__ fill,
                                int* __restrict__ csr_src, float* __restrict__ csr_attr,
                                int E, int n) {
    int i = blockIdx.x * blockDim.x + threadIdx.x;
    if (i < E) {
        int d = dst[i];
        int pos = row_ptr[d] + atomicAdd(&fill[d], 1);
        csr_src[pos] = src[i];
        csr_attr[pos] = eattr[i];
    } else if (i < E + n) {
        int v = i - E;
        int pos = row_ptr[v] + atomicAdd(&fill[v], 1);
        int c = deg[v];
        csr_src[pos] = v;
        csr_attr[pos] = asum[v] / (float)(c > 0 ? c : 1);   // mean, 0 if isolated
    }
}

// --- Dense transforms: XL = X@Wl, XR = X@Wr, LDS-tiled ---------------------
// Block = 256 threads handles TM=16 nodes. X tile staged in LDS (coalesced
// float4). Each thread owns one combined output column (cc<COUT -> Wl col,
// else Wr col) and MPG node-accumulators in registers. Inner loop: 4 W dword
// loads (coalesced, reused MPG times) + MPG broadcast ds_read_b128 + 4*MPG FMA.
template <int CIN, int COUT>
__global__ __launch_bounds__(256) void xform_tiled_kernel(
    const float* __restrict__ X, const float* __restrict__ Wl,
    const float* __restrict__ Wr, float* __restrict__ XL,
    float* __restrict__ XR, int n) {
    constexpr int TM = 16;
    constexpr int NCOLS = 2 * COUT;        // 256 (L1) or 128 (L2)
    constexpr int GROUPS = 256 / NCOLS;    // 1 or 2 node-groups
    constexpr int MPG = TM / GROUPS;       // 16 or 8 nodes per thread

    __shared__ float xs[TM][CIN];
    const int node0 = blockIdx.x * TM;

    // stage X tile: TM*CIN floats, coalesced float4
    constexpr int TOT4 = TM * CIN / 4;
    const float4* __restrict__ Xv = (const float4*)(X + (size_t)node0 * CIN);
    float4* xsv = (float4*)&xs[0][0];
    for (int idx = threadIdx.x; idx < TOT4; idx += 256) {
        int r = idx / (CIN / 4);
        xsv[idx] = (node0 + r < n) ? Xv[idx] : make_float4(0.f, 0.f, 0.f, 0.f);
    }
    __syncthreads();

    const int t  = threadIdx.x;
    const int g  = t / NCOLS;              // node group (uniform per wave)
    const int cc = t % NCOLS;              // combined column
    const float* __restrict__ W = (cc < COUT) ? Wl : Wr;  // uniform per wave
    float* __restrict__ Y       = (cc < COUT) ? XL : XR;
    const int c = cc & (COUT - 1);

    float acc[MPG];
#pragma unroll
    for (int i = 0; i < MPG; ++i) acc[i] = 0.f;

    for (int k = 0; k < CIN; k += 4) {
        float w0 = W[(k + 0) * COUT + c];
        float w1 = W[(k + 1) * COUT + c];
        float w2 = W[(k + 2) * COUT + c];
        float w3 = W[(k + 3) * COUT + c];
#pragma unroll
        for (int i = 0; i < MPG; ++i) {
            float4 xv = *(const float4*)&xs[g * MPG + i][k];  // broadcast read
            acc[i] = fmaf(xv.x, w0, acc[i]);
            acc[i] = fmaf(xv.y, w1, acc[i]);
            acc[i] = fmaf(xv.z, w2, acc[i]);
            acc[i] = fmaf(xv.w, w3, acc[i]);
        }
    }

#pragma unroll
    for (int i = 0; i < MPG; ++i) {
        int node = node0 + g * MPG + i;
        if (node < n) Y[(size_t)node * COUT + c] = acc[i];
    }
}

// --- Aggregation, C=128: one wave per node, lane owns channels {2l, 2l+1} --
// NOTE: XR may alias OUT (h overwrites xr1). Each wave reads only its own
// node's XR row (into registers, up front) and writes only its own OUT row,
// so the aliasing is hazard-free; restrict deliberately omitted on XR/OUT.
__global__ __launch_bounds__(256) void agg_c128_kernel(
    const float* __restrict__ XL, const float* XR,
    const int* __restrict__ row_ptr, const int* __restrict__ csr_src,
    const float* __restrict__ csr_attr, const float* __restrict__ We,
    const float* __restrict__ att, const float* __restrict__ bias,
    float* OUT, int n) {
    int wave = threadIdx.x >> 6;
    int lane = threadIdx.x & 63;
    int node = blockIdx.x * 4 + wave;
    if (node >= n) return;

    const float2 xr  = *(const float2*)(XR  + (size_t)node * 128 + lane * 2);
    const float2 wev = *(const float2*)(We  + lane * 2);
    const float2 atv = *(const float2*)(att + lane * 2);
    const float2 bv  = *(const float2*)(bias + lane * 2);

    int p = row_ptr[node], pe = row_ptr[node + 1];
    float m = -INFINITY, s = 0.f, a0 = 0.f, a1 = 0.f;
    for (; p < pe; ++p) {
        int   sj = csr_src[p];
        float ae = csr_attr[p];
        float2 xl = *(const float2*)(XL + (size_t)sj * 128 + lane * 2);
        float z0 = xl.x + xr.x + ae * wev.x;
        float z1 = xl.y + xr.y + ae * wev.y;
        z0 = (z0 > 0.f) ? z0 : NEG_SLOPE * z0;
        z1 = (z1 > 0.f) ? z1 : NEG_SLOPE * z1;
        float part = fmaf(atv.x, z0, atv.y * z1);
#pragma unroll
        for (int off = 32; off > 0; off >>= 1) part += __shfl_xor(part, off, 64);
        // online softmax update (identical math to max-subtracted softmax)
        float nm = fmaxf(m, part);
        float sc = expf(m - nm);      // first iter: expf(-inf)=0
        float w  = expf(part - nm);
        s  = s  * sc + w;
        a0 = a0 * sc + w * xl.x;
        a1 = a1 * sc + w * xl.y;
        m = nm;
    }
    float inv = 1.f / (s + 1e-16f);
    float o0 = a0 * inv + bv.x;
    float o1 = a1 * inv + bv.y;
    o0 = (o0 > 0.f) ? o0 : (expf(o0) - 1.f);   // elu
    o1 = (o1 > 0.f) ? o1 : (expf(o1) - 1.f);
    *(float2*)(OUT + (size_t)node * 128 + lane * 2) = make_float2(o0, o1);
}

// --- Aggregation, C=64: one wave per node, lane owns channel l -------------
__global__ __launch_bounds__(256) void agg_c64_kernel(
    const float* __restrict__ XL, const float* __restrict__ XR,
    const int* __restrict__ row_ptr, const int* __restrict__ csr_src,
    const float* __restrict__ csr_attr, const float* __restrict__ We,
    const float* __restrict__ att, const float* __restrict__ bias,
    float* __restrict__ OUT, int n) {
    int wave = threadIdx.x >> 6;
    int lane = threadIdx.x & 63;
    int node = blockIdx.x * 4 + wave;
    if (node >= n) return;

    float xr  = XR[(size_t)node * 64 + lane];
    float wev = We[lane];
    float atv = att[lane];
    float bv  = bias[lane];

    int p = row_ptr[node], pe = row_ptr[node + 1];
    float m = -INFINITY, s = 0.f, a0 = 0.f;
    for (; p < pe; ++p) {
        int   sj = csr_src[p];
        float ae = csr_attr[p];
        float xl = XL[(size_t)sj * 64 + lane];
        float z = xl + xr + ae * wev;
        z = (z > 0.f) ? z : NEG_SLOPE * z;
        float part = atv * z;
#pragma unroll
        for (int off = 32; off > 0; off >>= 1) part += __shfl_xor(part, off, 64);
        float nm = fmaxf(m, part);
        float sc = expf(m - nm);
        float w  = expf(part - nm);
        s  = s  * sc + w;
        a0 = a0 * sc + w * xl;
        m = nm;
    }
    float o = a0 / (s + 1e-16f) + bv;
    o = (o > 0.f) ? o : (expf(o) - 1.f);       // elu
    OUT[(size_t)node * 64 + lane] = o;
}

// ---------------------------------------------------------------------------
extern "C" void kernel_launch(void* const* d_in, const int* in_sizes, int n_in,
                              void* d_out, int out_size, void* d_ws, size_t ws_size,
                              hipStream_t stream) {
    const float* x    = (const float*)d_in[0];
    const int*   eidx = (const int*)  d_in[1];
    const float* ea   = (const float*)d_in[2];
    const float* Wl1  = (const float*)d_in[3];
    const float* Wr1  = (const float*)d_in[4];
    const float* We1  = (const float*)d_in[5];
    const float* att1 = (const float*)d_in[6];
    const float* b1   = (const float*)d_in[7];
    const float* Wl2  = (const float*)d_in[8];
    const float* Wr2  = (const float*)d_in[9];
    const float* We2  = (const float*)d_in[10];
    const float* att2 = (const float*)d_in[11];
    const float* b2   = (const float*)d_in[12];

    const int FIN = 128, H = 128, OUTC = 64;
    const int E  = in_sizes[2];          // edge_attr element count = #edges
    const int N  = in_sizes[0] / FIN;
    const int EP = E + N;                // with self-loops
    const int* src = eidx;               // edge_index[0]
    const int* dst = eidx + E;           // edge_index[1]

    // ---- workspace layout (256B aligned), peak ≈ 59 MB ----
    char* ws = (char*)d_ws;
    size_t off = 0;
    auto alloc = [&](size_t bytes) {
        size_t o = off;
        off += (bytes + 255) & ~(size_t)255;
        return o;
    };
    size_t deg_off  = alloc((size_t)N * 4);
    size_t asum_off = alloc((size_t)N * 4);
    size_t fill_off = alloc((size_t)N * 4);
    size_t zero_bytes = off;                       // deg|asum|fill zeroed together
    size_t rp_off    = alloc((size_t)(N + 1) * 4);
    size_t csrc_off  = alloc((size_t)EP * 4);
    size_t cattr_off = alloc((size_t)EP * 4);
    size_t xl1_off   = alloc((size_t)N * H * 4);   // reused as xl2|xr2 for layer 2
    size_t xr1_off   = alloc((size_t)N * H * 4);   // reused as h (safe aliasing)

    int*   deg   = (int*)  (ws + deg_off);
    float* asum  = (float*)(ws + asum_off);
    int*   fill  = (int*)  (ws + fill_off);
    int*   rp    = (int*)  (ws + rp_off);
    int*   csrc  = (int*)  (ws + csrc_off);
    float* cattr = (float*)(ws + cattr_off);
    float* xl1   = (float*)(ws + xl1_off);
    float* xr1   = (float*)(ws + xr1_off);
    float* h     = xr1;                                        // aliases xr1
    float* xl2   = (float*)(ws + xl1_off);                     // reuse xl1 region
    float* xr2   = (float*)(ws + xl1_off + (size_t)N * OUTC * 4);

    (void)ws_size; (void)n_in; (void)out_size;

    hipMemsetAsync(ws, 0, zero_bytes, stream);

    const int TB = 256;
    degree_kernel<<<(E + TB - 1) / TB, TB, 0, stream>>>(dst, ea, deg, asum, E);
    scan_rowptr_kernel<<<1, 1024, 0, stream>>>(deg, rp, N);
    csr_fill_kernel<<<(EP + TB - 1) / TB, TB, 0, stream>>>(src, dst, ea, deg, asum,
                                                           rp, fill, csrc, cattr, E, N);
    // layer 1
    xform_tiled_kernel<128, 128><<<(N + 15) / 16, 256, 0, stream>>>(x, Wl1, Wr1, xl1, xr1, N);
    agg_c128_kernel<<<(N + 3) / 4, 256, 0, stream>>>(xl1, xr1, rp, csrc, cattr,
                                                     We1, att1, b1, h, N);
    // layer 2
    xform_tiled_kernel<128, 64><<<(N + 15) / 16, 256, 0, stream>>>(h, Wl2, Wr2, xl2, xr2, N);
    agg_c64_kernel<<<(N + 3) / 4, 256, 0, stream>>>(xl2, xr2, rp, csrc, cattr,
                                                    We2, att2, b2, (float*)d_out, N);
}

// Round 6
// 357.884 us; speedup vs baseline: 2.1238x; 1.6061x over previous
//
#include <hip/hip_runtime.h>
#include <math.h>

// ---------------------------------------------------------------------------
// GATv2 x2 (heads=1) with mean-filled self-loops, fp32 end-to-end.
// CSR-by-dst built once (self-loop appended per node, src/attr packed int2);
// per layer: LDS-tiled dense transforms xl=x@Wl, xr=x@Wr, then per-node
// grouped online-softmax aggregation: 4 edges/wave-iter, 16 lanes/edge,
// per-group flash partials merged by a 2-level butterfly.
// ---------------------------------------------------------------------------

#define NEG_SLOPE 0.2f
#define MNEG -1e30f

// --- Phase A: in-degree + edge_attr sum per dst ----------------------------
__global__ void degree_kernel(const int* __restrict__ dst, const float* __restrict__ eattr,
                              int* __restrict__ deg, float* __restrict__ asum, int E) {
    int e = blockIdx.x * blockDim.x + threadIdx.x;
    if (e < E) {
        int d = dst[e];
        atomicAdd(&deg[d], 1);
        atomicAdd(&asum[d], eattr[e]);
    }
}

// --- Phase B: 3-kernel parallel scan of (deg[i]+1) -> row_ptr --------------
__global__ __launch_bounds__(1024) void scan_part_kernel(const int* __restrict__ deg,
                                                         int* __restrict__ partials, int n) {
    __shared__ int red[1024];
    int gid = blockIdx.x * 1024 + threadIdx.x;
    red[threadIdx.x] = (gid < n) ? (deg[gid] + 1) : 0;
    __syncthreads();
    for (int off = 512; off > 0; off >>= 1) {
        if (threadIdx.x < off) red[threadIdx.x] += red[threadIdx.x + off];
        __syncthreads();
    }
    if (threadIdx.x == 0) partials[blockIdx.x] = red[0];
}

__global__ __launch_bounds__(1024) void scan_blocksums_kernel(int* __restrict__ partials, int nb) {
    __shared__ int buf[1024];
    int t = threadIdx.x;
    int v = (t < nb) ? partials[t] : 0;
    buf[t] = v;
    __syncthreads();
    for (int off = 1; off < 1024; off <<= 1) {
        int a = (t >= off) ? buf[t - off] : 0;
        __syncthreads();
        buf[t] += a;
        __syncthreads();
    }
    if (t < nb) partials[t] = buf[t] - v;   // exclusive prefix
}

__global__ __launch_bounds__(1024) void scan_final_kernel(const int* __restrict__ deg,
                                                          const int* __restrict__ partials,
                                                          int* __restrict__ row_ptr, int n) {
    __shared__ int buf[1024];
    int gid = blockIdx.x * 1024 + threadIdx.x;
    int v = (gid < n) ? (deg[gid] + 1) : 0;
    buf[threadIdx.x] = v;
    __syncthreads();
    for (int off = 1; off < 1024; off <<= 1) {
        int a = (threadIdx.x >= off) ? buf[threadIdx.x - off] : 0;
        __syncthreads();
        buf[threadIdx.x] += a;
        __syncthreads();
    }
    if (gid < n) row_ptr[gid + 1] = partials[blockIdx.x] + buf[threadIdx.x];
    if (gid == 0) row_ptr[0] = 0;
}

// --- Phase C: scatter edges into CSR; append self-loop with mean attr ------
__global__ void csr_fill_kernel(const int* __restrict__ src, const int* __restrict__ dst,
                                const float* __restrict__ eattr,
                                const int* __restrict__ deg, const float* __restrict__ asum,
                                const int* __restrict__ row_ptr, int* __restrict__ fill,
                                int2* __restrict__ csr, int E, int n) {
    int i = blockIdx.x * blockDim.x + threadIdx.x;
    if (i < E) {
        int d = dst[i];
        int pos = row_ptr[d] + atomicAdd(&fill[d], 1);
        csr[pos] = make_int2(src[i], __float_as_int(eattr[i]));
    } else if (i < E + n) {
        int v = i - E;
        int pos = row_ptr[v] + atomicAdd(&fill[v], 1);
        int c = deg[v];
        float mean = asum[v] / (float)(c > 0 ? c : 1);   // mean, 0 if isolated
        csr[pos] = make_int2(v, __float_as_int(mean));
    }
}

// --- Dense transforms: XL = X@Wl, XR = X@Wr, LDS-tiled ---------------------
template <int CIN, int COUT>
__global__ __launch_bounds__(256) void xform_tiled_kernel(
    const float* __restrict__ X, const float* __restrict__ Wl,
    const float* __restrict__ Wr, float* __restrict__ XL,
    float* __restrict__ XR, int n) {
    constexpr int TM = 16;
    constexpr int NCOLS = 2 * COUT;        // 256 (L1) or 128 (L2)
    constexpr int GROUPS = 256 / NCOLS;    // 1 or 2 node-groups
    constexpr int MPG = TM / GROUPS;       // 16 or 8 nodes per thread

    __shared__ float xs[TM][CIN];
    const int node0 = blockIdx.x * TM;

    constexpr int TOT4 = TM * CIN / 4;
    const float4* __restrict__ Xv = (const float4*)(X + (size_t)node0 * CIN);
    float4* xsv = (float4*)&xs[0][0];
    for (int idx = threadIdx.x; idx < TOT4; idx += 256) {
        int r = idx / (CIN / 4);
        xsv[idx] = (node0 + r < n) ? Xv[idx] : make_float4(0.f, 0.f, 0.f, 0.f);
    }
    __syncthreads();

    const int t  = threadIdx.x;
    const int g  = t / NCOLS;              // node group (uniform per wave)
    const int cc = t % NCOLS;              // combined column
    const float* __restrict__ W = (cc < COUT) ? Wl : Wr;  // uniform per wave
    float* __restrict__ Y       = (cc < COUT) ? XL : XR;
    const int c = cc & (COUT - 1);

    float acc[MPG];
#pragma unroll
    for (int i = 0; i < MPG; ++i) acc[i] = 0.f;

    for (int k = 0; k < CIN; k += 4) {
        float w0 = W[(k + 0) * COUT + c];
        float w1 = W[(k + 1) * COUT + c];
        float w2 = W[(k + 2) * COUT + c];
        float w3 = W[(k + 3) * COUT + c];
#pragma unroll
        for (int i = 0; i < MPG; ++i) {
            float4 xv = *(const float4*)&xs[g * MPG + i][k];  // broadcast read
            acc[i] = fmaf(xv.x, w0, acc[i]);
            acc[i] = fmaf(xv.y, w1, acc[i]);
            acc[i] = fmaf(xv.z, w2, acc[i]);
            acc[i] = fmaf(xv.w, w3, acc[i]);
        }
    }

#pragma unroll
    for (int i = 0; i < MPG; ++i) {
        int node = node0 + g * MPG + i;
        if (node < n) Y[(size_t)node * COUT + c] = acc[i];
    }
}

// --- Grouped aggregation: one wave per node, 16 lanes per edge, 4 edges ----
// C = channels (128 or 64); lane l16 = lane&15 owns channels [l16*CPL, +CPL);
// group grp = lane>>4 owns edges p0+grp, p0+grp+4, ... with its own flash
// partial (m, s, acc[CPL]); partials merged by xor-16/32 butterfly at the end.
// NOTE: XR may alias OUT (h overwrites xr1). Each wave reads only its own
// node's XR row up front and writes only its own OUT row -> hazard-free;
// restrict deliberately omitted on XR/OUT.
template <int C>
__global__ __launch_bounds__(256) void agg_grouped_kernel(
    const float* __restrict__ XL, const float* XR,
    const int* __restrict__ row_ptr, const int2* __restrict__ csr,
    const float* __restrict__ We, const float* __restrict__ att,
    const float* __restrict__ bias, float* OUT, int n) {
    constexpr int CPL = C / 16;            // channels per lane (8 or 4)
    const int wave = threadIdx.x >> 6;
    const int lane = threadIdx.x & 63;
    const int node = blockIdx.x * 4 + wave;
    if (node >= n) return;
    const int l16 = lane & 15;
    const int grp = lane >> 4;
    const int cb  = l16 * CPL;

    float xr[CPL], wev[CPL], atv[CPL];
#pragma unroll
    for (int j = 0; j < CPL; j += 4) {
        *(float4*)&xr[j]  = *(const float4*)(XR  + (size_t)node * C + cb + j);
        *(float4*)&wev[j] = *(const float4*)(We  + cb + j);
        *(float4*)&atv[j] = *(const float4*)(att + cb + j);
    }

    const int p0 = row_ptr[node], pe = row_ptr[node + 1];
    float m = MNEG, s = 0.f;
    float acc[CPL];
#pragma unroll
    for (int j = 0; j < CPL; ++j) acc[j] = 0.f;

    // per-group strided edge loop (groups diverge only in trip count)
    for (int p = p0 + grp; p < pe; p += 4) {
        int2 ed = csr[p];                  // broadcast within group
        int   sj = ed.x;
        float ae = __int_as_float(ed.y);
        float xl[CPL];
        const float* xlp = XL + (size_t)sj * C + cb;
#pragma unroll
        for (int j = 0; j < CPL; j += 4) *(float4*)&xl[j] = *(const float4*)(xlp + j);

        float part = 0.f;
#pragma unroll
        for (int j = 0; j < CPL; ++j) {
            float z = fmaf(ae, wev[j], xl[j] + xr[j]);
            z = fmaxf(z, NEG_SLOPE * z);   // leaky_relu
            part = fmaf(atv[j], z, part);
        }
        // reduce within the 16-lane group
#pragma unroll
        for (int off = 1; off < 16; off <<= 1) part += __shfl_xor(part, off, 64);

        float nm = fmaxf(m, part);
        float e1 = expf(m - nm);           // m=MNEG first iter -> 0, finite input
        float w  = expf(part - nm);
        s = fmaf(s, e1, w);
#pragma unroll
        for (int j = 0; j < CPL; ++j) acc[j] = fmaf(acc[j], e1, w * xl[j]);
        m = nm;
    }

    // merge the 4 group partials (all lanes reconverged here)
#pragma unroll
    for (int off = 16; off <= 32; off <<= 1) {
        float mo = __shfl_xor(m, off, 64);
        float so = __shfl_xor(s, off, 64);
        float nm = fmaxf(m, mo);
        float e1 = expf(m - nm);           // empty group: m=mo=MNEG -> e=1, s/acc=0
        float e2 = expf(mo - nm);
        s = s * e1 + so * e2;
#pragma unroll
        for (int j = 0; j < CPL; ++j) {
            float ao = __shfl_xor(acc[j], off, 64);
            acc[j] = acc[j] * e1 + ao * e2;
        }
        m = nm;
    }

    if (grp == 0) {
        float inv = 1.f / (s + 1e-16f);
        float o[CPL];
#pragma unroll
        for (int j = 0; j < CPL; ++j) {
            float v = fmaf(acc[j], inv, bias[cb + j]);
            o[j] = (v > 0.f) ? v : (expf(v) - 1.f);   // elu
        }
#pragma unroll
        for (int j = 0; j < CPL; j += 4)
            *(float4*)(OUT + (size_t)node * C + cb + j) = *(const float4*)&o[j];
    }
}

// ---------------------------------------------------------------------------
extern "C" void kernel_launch(void* const* d_in, const int* in_sizes, int n_in,
                              void* d_out, int out_size, void* d_ws, size_t ws_size,
                              hipStream_t stream) {
    const float* x    = (const float*)d_in[0];
    const int*   eidx = (const int*)  d_in[1];
    const float* ea   = (const float*)d_in[2];
    const float* Wl1  = (const float*)d_in[3];
    const float* Wr1  = (const float*)d_in[4];
    const float* We1  = (const float*)d_in[5];
    const float* att1 = (const float*)d_in[6];
    const float* b1   = (const float*)d_in[7];
    const float* Wl2  = (const float*)d_in[8];
    const float* Wr2  = (const float*)d_in[9];
    const float* We2  = (const float*)d_in[10];
    const float* att2 = (const float*)d_in[11];
    const float* b2   = (const float*)d_in[12];

    const int FIN = 128, H = 128, OUTC = 64;
    const int E  = in_sizes[2];          // edge_attr element count = #edges
    const int N  = in_sizes[0] / FIN;
    const int EP = E + N;                // with self-loops
    const int NB = (N + 1023) / 1024;    // scan blocks (<=1024 assumed)
    const int* src = eidx;               // edge_index[0]
    const int* dst = eidx + E;           // edge_index[1]

    // ---- workspace layout (256B aligned), peak ≈ 59 MB ----
    char* ws = (char*)d_ws;
    size_t off = 0;
    auto alloc = [&](size_t bytes) {
        size_t o = off;
        off += (bytes + 255) & ~(size_t)255;
        return o;
    };
    size_t deg_off   = alloc((size_t)N * 4);
    size_t asum_off  = alloc((size_t)N * 4);
    size_t fill_off  = alloc((size_t)N * 4);
    size_t zero_bytes = off;                       // deg|asum|fill zeroed together
    size_t rp_off    = alloc((size_t)(N + 1) * 4);
    size_t part_off  = alloc((size_t)NB * 4);
    size_t csr_off   = alloc((size_t)EP * 8);      // packed (src, attr)
    size_t xl1_off   = alloc((size_t)N * H * 4);   // reused as xl2|xr2 for layer 2
    size_t xr1_off   = alloc((size_t)N * H * 4);   // reused as h (safe aliasing)

    int*   deg   = (int*)  (ws + deg_off);
    float* asum  = (float*)(ws + asum_off);
    int*   fill  = (int*)  (ws + fill_off);
    int*   rp    = (int*)  (ws + rp_off);
    int*   part  = (int*)  (ws + part_off);
    int2*  csr   = (int2*) (ws + csr_off);
    float* xl1   = (float*)(ws + xl1_off);
    float* xr1   = (float*)(ws + xr1_off);
    float* h     = xr1;                                        // aliases xr1
    float* xl2   = (float*)(ws + xl1_off);                     // reuse xl1 region
    float* xr2   = (float*)(ws + xl1_off + (size_t)N * OUTC * 4);

    (void)ws_size; (void)n_in; (void)out_size;

    hipMemsetAsync(ws, 0, zero_bytes, stream);

    const int TB = 256;
    degree_kernel<<<(E + TB - 1) / TB, TB, 0, stream>>>(dst, ea, deg, asum, E);
    scan_part_kernel<<<NB, 1024, 0, stream>>>(deg, part, N);
    scan_blocksums_kernel<<<1, 1024, 0, stream>>>(part, NB);
    scan_final_kernel<<<NB, 1024, 0, stream>>>(deg, part, rp, N);
    csr_fill_kernel<<<(EP + TB - 1) / TB, TB, 0, stream>>>(src, dst, ea, deg, asum,
                                                           rp, fill, csr, E, N);
    // layer 1
    xform_tiled_kernel<128, 128><<<(N + 15) / 16, 256, 0, stream>>>(x, Wl1, Wr1, xl1, xr1, N);
    agg_grouped_kernel<128><<<(N + 3) / 4, 256, 0, stream>>>(xl1, xr1, rp, csr,
                                                             We1, att1, b1, h, N);
    // layer 2
    xform_tiled_kernel<128, 64><<<(N + 15) / 16, 256, 0, stream>>>(h, Wl2, Wr2, xl2, xr2, N);
    agg_grouped_kernel<64><<<(N + 3) / 4, 256, 0, stream>>>(xl2, xr2, rp, csr,
                                                            We2, att2, b2, (float*)d_out, N);
}

// Round 7
// 339.692 us; speedup vs baseline: 2.2376x; 1.0536x over previous
//
#include <hip/hip_runtime.h>
#include <math.h>

// ---------------------------------------------------------------------------
// GATv2 x2 (heads=1) with mean-filled self-loops, fp32 end-to-end.
// CSR-by-dst built once (self-loop appended per node, src/attr packed int2);
// per layer: register-tiled dense GEMM xl|xr = x@[Wl|Wr] (32-node x NCOLS
// tile, 4x8 per-thread register block), then per-node grouped online-softmax
// aggregation: 4 edges/wave-iter, 16 lanes/edge, partials merged by butterfly.
// ---------------------------------------------------------------------------

#define NEG_SLOPE 0.2f
#define MNEG -1e30f

// --- Phase A: in-degree + edge_attr sum per dst ----------------------------
__global__ void degree_kernel(const int* __restrict__ dst, const float* __restrict__ eattr,
                              int* __restrict__ deg, float* __restrict__ asum, int E) {
    int e = blockIdx.x * blockDim.x + threadIdx.x;
    if (e < E) {
        int d = dst[e];
        atomicAdd(&deg[d], 1);
        atomicAdd(&asum[d], eattr[e]);
    }
}

// --- Phase B: 3-kernel parallel scan of (deg[i]+1) -> row_ptr --------------
__global__ __launch_bounds__(1024) void scan_part_kernel(const int* __restrict__ deg,
                                                         int* __restrict__ partials, int n) {
    __shared__ int red[1024];
    int gid = blockIdx.x * 1024 + threadIdx.x;
    red[threadIdx.x] = (gid < n) ? (deg[gid] + 1) : 0;
    __syncthreads();
    for (int off = 512; off > 0; off >>= 1) {
        if (threadIdx.x < off) red[threadIdx.x] += red[threadIdx.x + off];
        __syncthreads();
    }
    if (threadIdx.x == 0) partials[blockIdx.x] = red[0];
}

__global__ __launch_bounds__(1024) void scan_blocksums_kernel(int* __restrict__ partials, int nb) {
    __shared__ int buf[1024];
    int t = threadIdx.x;
    int v = (t < nb) ? partials[t] : 0;
    buf[t] = v;
    __syncthreads();
    for (int off = 1; off < 1024; off <<= 1) {
        int a = (t >= off) ? buf[t - off] : 0;
        __syncthreads();
        buf[t] += a;
        __syncthreads();
    }
    if (t < nb) partials[t] = buf[t] - v;   // exclusive prefix
}

__global__ __launch_bounds__(1024) void scan_final_kernel(const int* __restrict__ deg,
                                                          const int* __restrict__ partials,
                                                          int* __restrict__ row_ptr, int n) {
    __shared__ int buf[1024];
    int gid = blockIdx.x * 1024 + threadIdx.x;
    int v = (gid < n) ? (deg[gid] + 1) : 0;
    buf[threadIdx.x] = v;
    __syncthreads();
    for (int off = 1; off < 1024; off <<= 1) {
        int a = (threadIdx.x >= off) ? buf[threadIdx.x - off] : 0;
        __syncthreads();
        buf[threadIdx.x] += a;
        __syncthreads();
    }
    if (gid < n) row_ptr[gid + 1] = partials[blockIdx.x] + buf[threadIdx.x];
    if (gid == 0) row_ptr[0] = 0;
}

// --- Phase C: scatter edges into CSR; append self-loop with mean attr ------
__global__ void csr_fill_kernel(const int* __restrict__ src, const int* __restrict__ dst,
                                const float* __restrict__ eattr,
                                const int* __restrict__ deg, const float* __restrict__ asum,
                                const int* __restrict__ row_ptr, int* __restrict__ fill,
                                int2* __restrict__ csr, int E, int n) {
    int i = blockIdx.x * blockDim.x + threadIdx.x;
    if (i < E) {
        int d = dst[i];
        int pos = row_ptr[d] + atomicAdd(&fill[d], 1);
        csr[pos] = make_int2(src[i], __float_as_int(eattr[i]));
    } else if (i < E + n) {
        int v = i - E;
        int pos = row_ptr[v] + atomicAdd(&fill[v], 1);
        int c = deg[v];
        float mean = asum[v] / (float)(c > 0 ? c : 1);   // mean, 0 if isolated
        csr[pos] = make_int2(v, __float_as_int(mean));
    }
}

// --- Dense transforms: [XL|XR] = X @ [Wl|Wr], register-tiled ---------------
// Block = 256 threads, tile = TM=32 nodes x NCOLS cols. Thread owns A nodes
// x 8 cols (4 Wl + 4 Wr) = 8*A accumulators. X tile staged row-major in LDS
// once (linear copy, conflict-free); W staged in KCH-row chunks. Per k per
// thread: A broadcast x reads + 2 ds_read_b128 of W + 8*A FMAs.
template <int CIN, int COUT>
__global__ __launch_bounds__(256) void xform_gemm_kernel(
    const float* __restrict__ X, const float* __restrict__ Wl,
    const float* __restrict__ Wr, float* __restrict__ XL,
    float* __restrict__ XR, int n) {
    constexpr int TM = 32;
    constexpr int NCOLS = 2 * COUT;            // 256 (L1) or 128 (L2)
    constexpr int CT = NCOLS / 8;              // col-threads: 32 or 16
    constexpr int A = TM / (256 / CT);         // nodes per thread: 4 or 2
    constexpr int KCH = 16;

    __shared__ float xs[TM][CIN];              // 16 KB
    __shared__ float wsh[KCH][NCOLS];          // 16 KB (L1) / 8 KB (L2)

    const int node0 = blockIdx.x * TM;
    const int t = threadIdx.x;

    // stage X tile (row-major, coalesced float4, linear LDS writes)
    for (int idx = t; idx < TM * CIN / 4; idx += 256) {
        int r = idx / (CIN / 4);
        float4 v = (node0 + r < n)
                       ? ((const float4*)(X + (size_t)node0 * CIN))[idx]
                       : make_float4(0.f, 0.f, 0.f, 0.f);
        ((float4*)&xs[0][0])[idx] = v;
    }

    const int ct = t % CT;                     // col-thread id
    const int r0 = (t / CT) * A;               // first node row of this thread
    const int c0 = ct * 4;                     // base col within Wl (and Wr)

    float acc[A][8];
#pragma unroll
    for (int i = 0; i < A; ++i)
#pragma unroll
        for (int j = 0; j < 8; ++j) acc[i][j] = 0.f;

    for (int k0 = 0; k0 < CIN; k0 += KCH) {
        __syncthreads();                       // xs ready / prev chunk done
        // stage W chunk: wsh[kk][col], col<COUT from Wl, col>=COUT from Wr
        for (int idx = t; idx < KCH * NCOLS / 4; idx += 256) {
            int kk = idx / (NCOLS / 4);
            int col = (idx % (NCOLS / 4)) * 4;
            float4 v = (col < COUT)
                           ? *(const float4*)(Wl + (size_t)(k0 + kk) * COUT + col)
                           : *(const float4*)(Wr + (size_t)(k0 + kk) * COUT + (col - COUT));
            *(float4*)&wsh[kk][col] = v;
        }
        __syncthreads();
#pragma unroll
        for (int kk = 0; kk < KCH; ++kk) {
            float4 wl4 = *(const float4*)&wsh[kk][c0];
            float4 wr4 = *(const float4*)&wsh[kk][COUT + c0];
#pragma unroll
            for (int i = 0; i < A; ++i) {
                float xv = xs[r0 + i][k0 + kk];       // broadcast read
                acc[i][0] = fmaf(xv, wl4.x, acc[i][0]);
                acc[i][1] = fmaf(xv, wl4.y, acc[i][1]);
                acc[i][2] = fmaf(xv, wl4.z, acc[i][2]);
                acc[i][3] = fmaf(xv, wl4.w, acc[i][3]);
                acc[i][4] = fmaf(xv, wr4.x, acc[i][4]);
                acc[i][5] = fmaf(xv, wr4.y, acc[i][5]);
                acc[i][6] = fmaf(xv, wr4.z, acc[i][6]);
                acc[i][7] = fmaf(xv, wr4.w, acc[i][7]);
            }
        }
    }

#pragma unroll
    for (int i = 0; i < A; ++i) {
        int node = node0 + r0 + i;
        if (node < n) {
            *(float4*)(XL + (size_t)node * COUT + c0) =
                make_float4(acc[i][0], acc[i][1], acc[i][2], acc[i][3]);
            *(float4*)(XR + (size_t)node * COUT + c0) =
                make_float4(acc[i][4], acc[i][5], acc[i][6], acc[i][7]);
        }
    }
}

// --- Grouped aggregation: one wave per node, 16 lanes per edge, 4 edges ----
// C = channels (128 or 64); lane l16 = lane&15 owns channels [l16*CPL, +CPL);
// group grp = lane>>4 owns edges p0+grp, p0+grp+4, ... with its own flash
// partial (m, s, acc[CPL]); partials merged by xor-16/32 butterfly at the end.
// NOTE: XR may alias OUT (h overwrites xr1). Each wave reads only its own
// node's XR row up front and writes only its own OUT row -> hazard-free;
// restrict deliberately omitted on XR/OUT.
template <int C>
__global__ __launch_bounds__(256) void agg_grouped_kernel(
    const float* __restrict__ XL, const float* XR,
    const int* __restrict__ row_ptr, const int2* __restrict__ csr,
    const float* __restrict__ We, const float* __restrict__ att,
    const float* __restrict__ bias, float* OUT, int n) {
    constexpr int CPL = C / 16;            // channels per lane (8 or 4)
    const int wave = threadIdx.x >> 6;
    const int lane = threadIdx.x & 63;
    const int node = blockIdx.x * 4 + wave;
    if (node >= n) return;
    const int l16 = lane & 15;
    const int grp = lane >> 4;
    const int cb  = l16 * CPL;

    float xr[CPL], wev[CPL], atv[CPL];
#pragma unroll
    for (int j = 0; j < CPL; j += 4) {
        *(float4*)&xr[j]  = *(const float4*)(XR  + (size_t)node * C + cb + j);
        *(float4*)&wev[j] = *(const float4*)(We  + cb + j);
        *(float4*)&atv[j] = *(const float4*)(att + cb + j);
    }

    const int p0 = row_ptr[node], pe = row_ptr[node + 1];
    float m = MNEG, s = 0.f;
    float acc[CPL];
#pragma unroll
    for (int j = 0; j < CPL; ++j) acc[j] = 0.f;

    // per-group strided edge loop (groups diverge only in trip count)
    for (int p = p0 + grp; p < pe; p += 4) {
        int2 ed = csr[p];                  // broadcast within group
        int   sj = ed.x;
        float ae = __int_as_float(ed.y);
        float xl[CPL];
        const float* xlp = XL + (size_t)sj * C + cb;
#pragma unroll
        for (int j = 0; j < CPL; j += 4) *(float4*)&xl[j] = *(const float4*)(xlp + j);

        float part = 0.f;
#pragma unroll
        for (int j = 0; j < CPL; ++j) {
            float z = fmaf(ae, wev[j], xl[j] + xr[j]);
            z = fmaxf(z, NEG_SLOPE * z);   // leaky_relu
            part = fmaf(atv[j], z, part);
        }
        // reduce within the 16-lane group
#pragma unroll
        for (int off = 1; off < 16; off <<= 1) part += __shfl_xor(part, off, 64);

        float nm = fmaxf(m, part);
        float e1 = expf(m - nm);           // m=MNEG first iter -> 0, finite input
        float w  = expf(part - nm);
        s = fmaf(s, e1, w);
#pragma unroll
        for (int j = 0; j < CPL; ++j) acc[j] = fmaf(acc[j], e1, w * xl[j]);
        m = nm;
    }

    // merge the 4 group partials (all lanes reconverged here)
#pragma unroll
    for (int off = 16; off <= 32; off <<= 1) {
        float mo = __shfl_xor(m, off, 64);
        float so = __shfl_xor(s, off, 64);
        float nm = fmaxf(m, mo);
        float e1 = expf(m - nm);           // empty group: m=mo=MNEG -> e=1, s/acc=0
        float e2 = expf(mo - nm);
        s = s * e1 + so * e2;
#pragma unroll
        for (int j = 0; j < CPL; ++j) {
            float ao = __shfl_xor(acc[j], off, 64);
            acc[j] = acc[j] * e1 + ao * e2;
        }
        m = nm;
    }

    if (grp == 0) {
        float inv = 1.f / (s + 1e-16f);
        float o[CPL];
#pragma unroll
        for (int j = 0; j < CPL; ++j) {
            float v = fmaf(acc[j], inv, bias[cb + j]);
            o[j] = (v > 0.f) ? v : (expf(v) - 1.f);   // elu
        }
#pragma unroll
        for (int j = 0; j < CPL; j += 4)
            *(float4*)(OUT + (size_t)node * C + cb + j) = *(const float4*)&o[j];
    }
}

// ---------------------------------------------------------------------------
extern "C" void kernel_launch(void* const* d_in, const int* in_sizes, int n_in,
                              void* d_out, int out_size, void* d_ws, size_t ws_size,
                              hipStream_t stream) {
    const float* x    = (const float*)d_in[0];
    const int*   eidx = (const int*)  d_in[1];
    const float* ea   = (const float*)d_in[2];
    const float* Wl1  = (const float*)d_in[3];
    const float* Wr1  = (const float*)d_in[4];
    const float* We1  = (const float*)d_in[5];
    const float* att1 = (const float*)d_in[6];
    const float* b1   = (const float*)d_in[7];
    const float* Wl2  = (const float*)d_in[8];
    const float* Wr2  = (const float*)d_in[9];
    const float* We2  = (const float*)d_in[10];
    const float* att2 = (const float*)d_in[11];
    const float* b2   = (const float*)d_in[12];

    const int FIN = 128, H = 128, OUTC = 64;
    const int E  = in_sizes[2];          // edge_attr element count = #edges
    const int N  = in_sizes[0] / FIN;
    const int EP = E + N;                // with self-loops
    const int NB = (N + 1023) / 1024;    // scan blocks (<=1024 assumed)
    const int* src = eidx;               // edge_index[0]
    const int* dst = eidx + E;           // edge_index[1]

    // ---- workspace layout (256B aligned), peak ≈ 59 MB ----
    char* ws = (char*)d_ws;
    size_t off = 0;
    auto alloc = [&](size_t bytes) {
        size_t o = off;
        off += (bytes + 255) & ~(size_t)255;
        return o;
    };
    size_t deg_off   = alloc((size_t)N * 4);
    size_t asum_off  = alloc((size_t)N * 4);
    size_t fill_off  = alloc((size_t)N * 4);
    size_t zero_bytes = off;                       // deg|asum|fill zeroed together
    size_t rp_off    = alloc((size_t)(N + 1) * 4);
    size_t part_off  = alloc((size_t)NB * 4);
    size_t csr_off   = alloc((size_t)EP * 8);      // packed (src, attr)
    size_t xl1_off   = alloc((size_t)N * H * 4);   // reused as xl2|xr2 for layer 2
    size_t xr1_off   = alloc((size_t)N * H * 4);   // reused as h (safe aliasing)

    int*   deg   = (int*)  (ws + deg_off);
    float* asum  = (float*)(ws + asum_off);
    int*   fill  = (int*)  (ws + fill_off);
    int*   rp    = (int*)  (ws + rp_off);
    int*   part  = (int*)  (ws + part_off);
    int2*  csr   = (int2*) (ws + csr_off);
    float* xl1   = (float*)(ws + xl1_off);
    float* xr1   = (float*)(ws + xr1_off);
    float* h     = xr1;                                        // aliases xr1
    float* xl2   = (float*)(ws + xl1_off);                     // reuse xl1 region
    float* xr2   = (float*)(ws + xl1_off + (size_t)N * OUTC * 4);

    (void)ws_size; (void)n_in; (void)out_size;

    hipMemsetAsync(ws, 0, zero_bytes, stream);

    const int TB = 256;
    degree_kernel<<<(E + TB - 1) / TB, TB, 0, stream>>>(dst, ea, deg, asum, E);
    scan_part_kernel<<<NB, 1024, 0, stream>>>(deg, part, N);
    scan_blocksums_kernel<<<1, 1024, 0, stream>>>(part, NB);
    scan_final_kernel<<<NB, 1024, 0, stream>>>(deg, part, rp, N);
    csr_fill_kernel<<<(EP + TB - 1) / TB, TB, 0, stream>>>(src, dst, ea, deg, asum,
                                                           rp, fill, csr, E, N);
    // layer 1
    xform_gemm_kernel<128, 128><<<(N + 31) / 32, 256, 0, stream>>>(x, Wl1, Wr1, xl1, xr1, N);
    agg_grouped_kernel<128><<<(N + 3) / 4, 256, 0, stream>>>(xl1, xr1, rp, csr,
                                                             We1, att1, b1, h, N);
    // layer 2
    xform_gemm_kernel<128, 64><<<(N + 31) / 32, 256, 0, stream>>>(h, Wl2, Wr2, xl2, xr2, N);
    agg_grouped_kernel<64><<<(N + 3) / 4, 256, 0, stream>>>(xl2, xr2, rp, csr,
                                                            We2, att2, b2, (float*)d_out, N);
}